// Round 7
// baseline (440.550 us; speedup 1.0000x reference)
//
#include <hip/hip_runtime.h>
#include <hip/hip_bf16.h>
#include <hip/hip_fp16.h>
#include <stdint.h>
#include <stddef.h>
#include <string.h>

#define D_EMB 1024
#define SEQ   2048
#define BATCH 4

typedef short bf16x8  __attribute__((ext_vector_type(8)));
typedef short short8  __attribute__((ext_vector_type(8)));
typedef float f32x4   __attribute__((ext_vector_type(4)));

#define AS1 __attribute__((address_space(1)))
#define AS3 __attribute__((address_space(3)))

static __device__ __forceinline__ void async_copy16(const void* g, void* l) {
  __builtin_amdgcn_global_load_lds((const AS1 void*)g, (AS3 void*)l, 16, 0, 0);
}

// ============================================================================
// R7 = R6 resubmit (R6 bench died at container level — infra, not kernel; the
// smpv kernel audits clean on bounds/LDS-size/sync/frag-maps).
// Structure: R4-verbatim prep/qkv/scores + fused smpv (softmax+PV):
//  - kills P buffer (33.5MB W + 33.5MB R), softmax kernel, one launch.
//  - per block: 32 q-rows x full e=1024; grid (64,1,4) = 256 blocks = 1 round.
//  - pass1: row max (row == 16-lane group, shfl-only reduce)
//  - pass2: exp(v-m) -> UNNORMALIZED bf16 P in LDS (row stride 2056 elems =
//    4112B, breaks 4096B bank alias); 1/l deferred to f32 epilogue.
//  - PV: no barriers in K-loop; A-frags from LDS reused across 16 e-tiles;
//    B (Vt) streamed from global (V_b 4.2MB is L2-resident; 64 co-batch
//    blocks walk the same kc order). acc[16] f32x4/thread.
// R2 LESSON: no mid-loop accumulator stores. R5 LESSON: no split-K atomics.
// ============================================================================

#define BAR     __builtin_amdgcn_s_barrier()
#define VMCNT6  asm volatile("s_waitcnt vmcnt(6)" ::: "memory")
#define VMCNT0  asm volatile("s_waitcnt vmcnt(0)" ::: "memory")

#define STAGE_A(buf, h, kt) do {                                              \
    const __hip_bfloat16* _g = gA + (size_t)((h) * 128) * lda + ((kt) << 6);  \
    char* _l = (char*)sA + (buf) * 32768 + (h) * 16384 + wave * 1024;         \
    async_copy16(_g, _l);                                                     \
    async_copy16(_g + (size_t)64 * lda, _l + 8192);                           \
  } while (0)
#define STAGE_B(buf, h, kt) do {                                              \
    const __hip_bfloat16* _g = gB + (size_t)((h) * 128) * ldb + ((kt) << 6);  \
    char* _l = (char*)sB + (buf) * 32768 + (h) * 16384 + wave * 1024;         \
    async_copy16(_g, _l);                                                     \
    async_copy16(_g + (size_t)64 * ldb, _l + 8192);                           \
  } while (0)

#define LOAD_A(aF, lbuf, h) do {                                              \
    const __hip_bfloat16* _b = (lbuf) + (wr * 128 + (h) * 64 + lr) * 64;      \
    _Pragma("unroll")                                                         \
    for (int _i = 0; _i < 4; _i++) {                                          \
      aF[_i][0] = *(const bf16x8*)&_b[_i * 1024 + pc0];                       \
      aF[_i][1] = *(const bf16x8*)&_b[_i * 1024 + pc1];                       \
    }                                                                         \
  } while (0)
#define LOAD_B(bF, lbuf, g) do {                                              \
    const __hip_bfloat16* _b = (lbuf) + (wc * 64 + (g) * 32 + lr) * 64;       \
    _Pragma("unroll")                                                         \
    for (int _j = 0; _j < 2; _j++) {                                          \
      bF[_j][0] = *(const bf16x8*)&_b[_j * 1024 + pc0];                       \
      bF[_j][1] = *(const bf16x8*)&_b[_j * 1024 + pc1];                       \
    }                                                                         \
  } while (0)

#define MFMA_Q(aF, bF, h, g) do {                                             \
    __builtin_amdgcn_s_setprio(1);                                            \
    _Pragma("unroll")                                                         \
    for (int _i = 0; _i < 4; _i++)                                            \
      _Pragma("unroll")                                                       \
      for (int _j = 0; _j < 2; _j++) {                                        \
        acc[(h) * 4 + _i][(g) * 2 + _j] =                                     \
          __builtin_amdgcn_mfma_f32_16x16x32_bf16(aF[_i][0], bF[_j][0],       \
              acc[(h) * 4 + _i][(g) * 2 + _j], 0, 0, 0);                      \
        acc[(h) * 4 + _i][(g) * 2 + _j] =                                     \
          __builtin_amdgcn_mfma_f32_16x16x32_bf16(aF[_i][1], bF[_j][1],       \
              acc[(h) * 4 + _i][(g) * 2 + _j], 0, 0, 0);                      \
      }                                                                       \
    __builtin_amdgcn_s_setprio(0);                                            \
  } while (0)

#define ZERO_ACC(acc)                         \
  {                                           \
    f32x4 _z = {0.f, 0.f, 0.f, 0.f};          \
    _Pragma("unroll")                         \
    for (int _i = 0; _i < 8; _i++)            \
      _Pragma("unroll")                       \
      for (int _j = 0; _j < 4; _j++)          \
        acc[_i][_j] = _z;                     \
  }

// ---------------- 256^2-tile 8-phase core (R4-verified, frozen) ----------------
static __device__ __forceinline__ void gemm256(
    const __hip_bfloat16* __restrict__ A, int lda,
    const __hip_bfloat16* __restrict__ Bt, int ldb,
    int K, f32x4 (&acc)[8][4])
{
  __shared__ __hip_bfloat16 sA[2][128 * 64 * 2];   // 64 KiB
  __shared__ __hip_bfloat16 sB[2][128 * 64 * 2];   // 64 KiB

  const int t    = threadIdx.x;   // 0..511
  const int wave = t >> 6;
  const int lane = t & 63;
  const int quad = lane >> 4;
  const int lr   = lane & 15;
  const int wr   = wave >> 2;     // 0..1  (M)
  const int wc   = wave & 3;      // 0..3  (N)

  const int r0 = t >> 3;
  const int cs = (((t & 7) ^ (r0 & 7)) << 3);
  const __hip_bfloat16* gA = A  + (size_t)r0 * lda + cs;
  const __hip_bfloat16* gB = Bt + (size_t)r0 * ldb + cs;

  const int pc0 = ((quad)     ^ (lr & 7)) << 3;
  const int pc1 = ((quad + 4) ^ (lr & 7)) << 3;

  const __hip_bfloat16* const lA0 = sA[0];
  const __hip_bfloat16* const lA1 = sA[1];
  const __hip_bfloat16* const lB0 = sB[0];
  const __hip_bfloat16* const lB1 = sB[1];

  const int nt    = K >> 6;
  const int niter = nt >> 1;

  // prologue: T0 complete (8 copies) + T1 B-lo,B-hi,A-lo (6 in flight).
  STAGE_A(0, 0, 0);
  STAGE_A(0, 1, 0);
  STAGE_B(0, 0, 0);
  STAGE_B(0, 1, 0);
  STAGE_B(1, 0, 1);
  STAGE_B(1, 1, 1);
  STAGE_A(1, 0, 1);
  VMCNT6;
  BAR;

  bf16x8 aF[4][2], bFa[2][2], bFb[2][2];

  for (int j = 0; j < niter - 1; ++j) {
    const int tb = 2 * j + 1, tc = tb + 1, td = tb + 2;

    LOAD_A(aF, lA0, 0); LOAD_B(bFa, lB0, 0);
    STAGE_A(1, 1, tb);
    BAR; MFMA_Q(aF, bFa, 0, 0); BAR;

    LOAD_B(bFb, lB0, 1);
    BAR; MFMA_Q(aF, bFb, 0, 1); BAR;

    LOAD_A(aF, lA0, 1);
    STAGE_B(0, 0, tc);
    BAR; MFMA_Q(aF, bFb, 1, 1); BAR;

    STAGE_B(0, 1, tc);
    STAGE_A(0, 0, tc);
    VMCNT6;
    BAR; MFMA_Q(aF, bFa, 1, 0); BAR;

    LOAD_A(aF, lA1, 0); LOAD_B(bFa, lB1, 0);
    STAGE_A(0, 1, tc);
    BAR; MFMA_Q(aF, bFa, 0, 0); BAR;

    LOAD_B(bFb, lB1, 1);
    BAR; MFMA_Q(aF, bFb, 0, 1); BAR;

    LOAD_A(aF, lA1, 1);
    STAGE_B(1, 0, td);
    BAR; MFMA_Q(aF, bFb, 1, 1); BAR;

    STAGE_B(1, 1, td);
    STAGE_A(1, 0, td);
    VMCNT6;
    BAR; MFMA_Q(aF, bFa, 1, 0); BAR;
  }

  {
    const int tb = nt - 1;
    LOAD_A(aF, lA0, 0); LOAD_B(bFa, lB0, 0);
    STAGE_A(1, 1, tb);
    BAR; MFMA_Q(aF, bFa, 0, 0); BAR;

    LOAD_B(bFb, lB0, 1);
    BAR; MFMA_Q(aF, bFb, 0, 1); BAR;

    LOAD_A(aF, lA0, 1);
    BAR; MFMA_Q(aF, bFb, 1, 1); BAR;

    VMCNT0;
    BAR; MFMA_Q(aF, bFa, 1, 0); BAR;

    LOAD_A(aF, lA1, 0); LOAD_B(bFa, lB1, 0);
    BAR; MFMA_Q(aF, bFa, 0, 0); BAR;

    LOAD_B(bFb, lB1, 1);
    BAR; MFMA_Q(aF, bFb, 0, 1); BAR;

    LOAD_A(aF, lA1, 1);
    BAR; MFMA_Q(aF, bFb, 1, 1); BAR;

    MFMA_Q(aF, bFa, 1, 0);
  }
}

// ---------------- fused prep: z<3 -> transpose+cast W; z==3 -> cast x ----------------
__global__ __launch_bounds__(256) void prep_kernel(
    const float* __restrict__ x,
    const float* __restrict__ Wq,
    const float* __restrict__ Wk,
    const float* __restrict__ Wv,
    __hip_bfloat16* __restrict__ xb,
    __hip_bfloat16* __restrict__ Wt3)
{
  const int tx = threadIdx.x, ty = threadIdx.y;  // (32,8)
  if (blockIdx.z == 3) {
    const int tid = ty * 32 + tx;
    const size_t base = ((size_t)blockIdx.y * 32 + blockIdx.x) * 8192;
#pragma unroll
    for (int p = 0; p < 8; p++) {
      const size_t i = base + p * 1024 + tid * 4;
      const float4 v = *(const float4*)(x + i);
      __hip_bfloat16 o[4] = {__float2bfloat16(v.x), __float2bfloat16(v.y),
                             __float2bfloat16(v.z), __float2bfloat16(v.w)};
      *(uint64_t*)(xb + i) = *(uint64_t*)o;
    }
    return;
  }
  const float* src = (blockIdx.z == 0) ? Wq : (blockIdx.z == 1) ? Wk : Wv;
  __hip_bfloat16* dst = Wt3 + (size_t)blockIdx.z * D_EMB * D_EMB;
  __shared__ __hip_bfloat16 tile[32][33];
  const int x0 = blockIdx.x * 32;  // e
  const int y0 = blockIdx.y * 32;  // d
#pragma unroll
  for (int i = 0; i < 32; i += 8)
    tile[ty + i][tx] = __float2bfloat16(src[(size_t)(y0 + ty + i) * D_EMB + (x0 + tx)]);
  __syncthreads();
#pragma unroll
  for (int i = 0; i < 32; i += 8)
    dst[(size_t)(x0 + ty + i) * D_EMB + (y0 + tx)] = tile[tx][ty + i];
}

// ---------------- QKV projections (R4-verbatim: per-tile 256^2, 8-phase) ----------------
__global__ __launch_bounds__(512, 2) void qkv_kernel(
    const __hip_bfloat16* __restrict__ xb,
    const __hip_bfloat16* __restrict__ Wt3,
    const float* __restrict__ bq,
    const float* __restrict__ bk,
    const float* __restrict__ bv,
    __hip_bfloat16* __restrict__ Q,
    __hip_bfloat16* __restrict__ Kb,
    __hip_bfloat16* __restrict__ Vt)
{
  const int mat = blockIdx.z;
  const int m0  = blockIdx.x * 256;
  const int n0  = blockIdx.y * 256;

  f32x4 acc[8][4];
  ZERO_ACC(acc);

  gemm256(xb + (size_t)m0 * D_EMB, D_EMB,
          Wt3 + (size_t)mat * D_EMB * D_EMB + (size_t)n0 * D_EMB, D_EMB,
          D_EMB, acc);

  const float* bias = (mat == 0) ? bq : (mat == 1) ? bk : bv;

  const int t = threadIdx.x;
  const int wave = t >> 6, lane = t & 63;
  const int quad = lane >> 4, lr = lane & 15;
  const int wr = wave >> 2, wc = wave & 3;

#pragma unroll
  for (int i = 0; i < 8; i++) {
#pragma unroll
    for (int j = 0; j < 4; j++) {
      const int n = n0 + wc * 64 + j * 16 + lr;
      const float bb = bias[n];
      const int mbase = m0 + wr * 128 + i * 16 + quad * 4;
      if (mat == 2) {
        const int b = mbase >> 11, s = mbase & 2047;
        __hip_bfloat16 pk[4];
#pragma unroll
        for (int r = 0; r < 4; r++) pk[r] = __float2bfloat16(acc[i][j][r] + bb);
        *(uint64_t*)&Vt[(size_t)b * D_EMB * SEQ + (size_t)n * SEQ + s] = *(uint64_t*)pk;
      } else {
        __hip_bfloat16* dst = (mat == 0) ? Q : Kb;
#pragma unroll
        for (int r = 0; r < 4; r++)
          dst[(size_t)(mbase + r) * D_EMB + n] = __float2bfloat16(acc[i][j][r] + bb);
      }
    }
  }
}

// ---------------- scores = Q @ K^T * scale (fp16 out) ----------------
__global__ __launch_bounds__(512, 2) void scores_kernel(
    const __hip_bfloat16* __restrict__ Q,
    const __hip_bfloat16* __restrict__ Kb,
    __half* __restrict__ Sc)
{
  const int b  = blockIdx.z;
  const int m0 = blockIdx.y * 256;  // s_q
  const int n0 = blockIdx.x * 256;  // s_k

  f32x4 acc[8][4];
  ZERO_ACC(acc);

  gemm256(Q  + (size_t)b * SEQ * D_EMB + (size_t)m0 * D_EMB, D_EMB,
          Kb + (size_t)b * SEQ * D_EMB + (size_t)n0 * D_EMB, D_EMB,
          D_EMB, acc);

  __half* out = Sc + (size_t)b * SEQ * SEQ;
  const float scale = 0.03125f;  // 1/sqrt(1024)

  const int t = threadIdx.x;
  const int wave = t >> 6, lane = t & 63;
  const int quad = lane >> 4, lr = lane & 15;
  const int wr = wave >> 2, wc = wave & 3;

#pragma unroll
  for (int i = 0; i < 8; i++)
#pragma unroll
    for (int j = 0; j < 4; j++) {
      const int n = n0 + wc * 64 + j * 16 + lr;
#pragma unroll
      for (int r = 0; r < 4; r++) {
        const int m = m0 + wr * 128 + i * 16 + quad * 4 + r;
        out[(size_t)m * SEQ + n] = __float2half(acc[i][j][r] * scale);
      }
    }
}

// ---------------- fused softmax + PV ----------------
// Block: 32 q-rows x full e=1024. Grid (64, 1, 4) = 256 blocks = one round.
// LDS row stride 2056 elems (4112 B) -> rows rotate 4 banks (no 4096B alias).
#define PROW 2056
__global__ __launch_bounds__(512, 1) void smpv_kernel(
    const __half* __restrict__ Sc,
    const __hip_bfloat16* __restrict__ Vt,
    float* __restrict__ out)
{
  __shared__ __hip_bfloat16 ldsP[32 * PROW];   // 131,584 B
  __shared__ float linv[32];

  const int b  = blockIdx.z;
  const int m0 = blockIdx.x * 32;

  const int t    = threadIdx.x;       // 0..511
  const int row  = t >> 4;            // 0..31 : q-row (16 threads per row)
  const int col0 = (t & 15) * 16;     // elem base; +p*256 strides

  const __half* src = Sc + ((size_t)b * SEQ + (m0 + row)) * SEQ;

  // pass 1: row max (each thread covers 8 strips of 16 elems = 2 x 16B loads)
  float vmax = -3.0e38f;
#pragma unroll
  for (int p = 0; p < 16; p++) {
    const int off = (p >> 1) * 256 + (p & 1) * 8;
    const short8 rv = *(const short8*)(src + col0 + off);
#pragma unroll
    for (int i = 0; i < 8; i++) {
      __half h; const short sv = rv[i]; memcpy(&h, &sv, 2);
      vmax = fmaxf(vmax, __half2float(h));
    }
  }
#pragma unroll
  for (int o = 1; o < 16; o <<= 1) vmax = fmaxf(vmax, __shfl_xor(vmax, o));

  // pass 2: exp(v - max) -> unnormalized bf16 P in LDS; accumulate l
  float lsum = 0.f;
#pragma unroll
  for (int p = 0; p < 16; p++) {
    const int off = (p >> 1) * 256 + (p & 1) * 8;   // 16B granules
    const short8 rv = *(const short8*)(src + col0 + off);
    short8 ov;
#pragma unroll
    for (int i = 0; i < 8; i++) {
      __half h; const short sv = rv[i]; memcpy(&h, &sv, 2);
      const float e = __expf(__half2float(h) - vmax);
      lsum += e;
      const __hip_bfloat16 eb = __float2bfloat16(e);
      short so; memcpy(&so, &eb, 2);
      ov[i] = so;
    }
    *(short8*)&ldsP[(size_t)row * PROW + col0 + off] = ov;
  }
#pragma unroll
  for (int o = 1; o < 16; o <<= 1) lsum += __shfl_xor(lsum, o);
  if ((t & 15) == 0) linv[row] = 1.f / lsum;
  __syncthreads();

  // PV: acc[16] f32x4; A-frags from LDS (reused over 16 e-tiles), B from global.
  const int wave = t >> 6, lane = t & 63;
  const int quad = lane >> 4, lr = lane & 15;
  const int wr = wave >> 2;           // 0..1 : rows wr*16..+16
  const int wc = wave & 3;            // e-range wc*256

  f32x4 acc[16];
  {
    f32x4 z = {0.f, 0.f, 0.f, 0.f};
#pragma unroll
    for (int j = 0; j < 16; j++) acc[j] = z;
  }

  const __hip_bfloat16* aRow  = &ldsP[(size_t)(wr * 16 + lr) * PROW + quad * 8];
  const __hip_bfloat16* bBase = Vt + (size_t)b * D_EMB * SEQ
                                   + (size_t)(wc * 256 + lr) * SEQ + quad * 8;

  for (int kc = 0; kc < 32; kc++) {
    const int k0 = kc * 64;
    const bf16x8 a0 = *(const bf16x8*)(aRow + k0);
    const bf16x8 a1 = *(const bf16x8*)(aRow + k0 + 32);
#pragma unroll
    for (int j = 0; j < 16; j++) {
      const bf16x8 b0 = *(const bf16x8*)(bBase + (size_t)j * 16 * SEQ + k0);
      const bf16x8 b1 = *(const bf16x8*)(bBase + (size_t)j * 16 * SEQ + k0 + 32);
      acc[j] = __builtin_amdgcn_mfma_f32_16x16x32_bf16(a0, b0, acc[j], 0, 0, 0);
      acc[j] = __builtin_amdgcn_mfma_f32_16x16x32_bf16(a1, b1, acc[j], 0, 0, 0);
    }
  }

  // epilogue: out[m][e] = acc * (1/l[row])   (rows: quad*4+r; cols: lr)
  float il[4];
#pragma unroll
  for (int r = 0; r < 4; r++) il[r] = linv[wr * 16 + quad * 4 + r];

  float* o = out + (size_t)b * SEQ * D_EMB;
  const int orow = m0 + wr * 16 + quad * 4;
  const int e0   = wc * 256 + lr;
#pragma unroll
  for (int j = 0; j < 16; j++)
#pragma unroll
    for (int r = 0; r < 4; r++)
      o[(size_t)(orow + r) * D_EMB + e0 + j * 16] = acc[j][r] * il[r];
}

extern "C" void kernel_launch(void* const* d_in, const int* in_sizes, int n_in,
                              void* d_out, int out_size, void* d_ws, size_t ws_size,
                              hipStream_t stream) {
  const float* x  = (const float*)d_in[0];
  const float* Wq = (const float*)d_in[1];
  const float* bq = (const float*)d_in[2];
  const float* Wk = (const float*)d_in[3];
  const float* bk = (const float*)d_in[4];
  const float* Wv = (const float*)d_in[5];
  const float* bv = (const float*)d_in[6];
  float* out = (float*)d_out;

  char* ws = (char*)d_ws;
  __hip_bfloat16* xb  = (__hip_bfloat16*)(ws);
  __hip_bfloat16* Wt3 = (__hip_bfloat16*)(ws + 16777216);
  __hip_bfloat16* Q   = (__hip_bfloat16*)(ws + 23068672);
  __hip_bfloat16* Kb  = (__hip_bfloat16*)(ws + 39845888);
  __hip_bfloat16* Vt  = (__hip_bfloat16*)(ws + 56623104);
  __half*         Sc  = (__half*)        (ws + 73400320);   // 32 MB fp16
  // total = 73400320 + 33554432 = 106,954,752 bytes (~102 MB)

  prep_kernel  <<<dim3(32, 32, 4), dim3(32, 8), 0, stream>>>(x, Wq, Wk, Wv, xb, Wt3);
  qkv_kernel   <<<dim3(32, 4, 3),  512,        0, stream>>>(xb, Wt3, bq, bk, bv, Q, Kb, Vt);
  scores_kernel<<<dim3(8, 8, 4),   512,        0, stream>>>(Q, Kb, Sc);
  smpv_kernel  <<<dim3(64, 1, 4),  512,        0, stream>>>(Sc, Vt, out);
}

// Round 8
// 265.994 us; speedup vs baseline: 1.6562x; 1.6562x over previous
//
#include <hip/hip_runtime.h>
#include <hip/hip_bf16.h>
#include <hip/hip_fp16.h>
#include <stdint.h>
#include <stddef.h>
#include <string.h>

#define D_EMB 1024
#define SEQ   2048
#define BATCH 4

typedef short bf16x8  __attribute__((ext_vector_type(8)));
typedef short short8  __attribute__((ext_vector_type(8)));
typedef float f32x4   __attribute__((ext_vector_type(4)));

#define AS1 __attribute__((address_space(1)))
#define AS3 __attribute__((address_space(3)))

static __device__ __forceinline__ void async_copy16(const void* g, void* l) {
  __builtin_amdgcn_global_load_lds((const AS1 void*)g, (AS3 void*)l, 16, 0, 0);
}

// ============================================================================
// R8 = byte-exact revert to the R4 anchor (best verified: 267.2 us; R0's
// 128^2 variant 265.4 is statistically tied). Session ledger:
//   R0 265.4 | R1 270.9 | R2 303 (persistent: spill) | R3 267.3 | R4 267.2
//   R5 363 (split-K atomics + weight-trick) | R7 441 (smpv fusion:
//   786K bank conflicts, uncoalesced V, MfmaUtil 5.5).
// Every structural departure from the R0/R4 plateau regressed; the four
// in-band pipelines differ structurally (2-phase vs 8-phase, tile shapes),
// i.e. the ~267us level is decomposition-bound at HIP level (MfmaUtil ~26,
// HBM ~16%, conflicts 0) — the documented path beyond is hand-asm-class
// K-loop scheduling (m201-exact / hand-asm), not reachable by the variants
// tried here.
// R2 LESSON: no mid-loop accumulator stores. R5 LESSON: no split-K atomics.
// R7 LESSON: PV fusion needs full staging structure, not naive streaming.
// ============================================================================

#define BAR     __builtin_amdgcn_s_barrier()
#define VMCNT6  asm volatile("s_waitcnt vmcnt(6)" ::: "memory")
#define VMCNT4  asm volatile("s_waitcnt vmcnt(4)" ::: "memory")
#define VMCNT0  asm volatile("s_waitcnt vmcnt(0)" ::: "memory")

#define STAGE_A(buf, h, kt) do {                                              \
    const __hip_bfloat16* _g = gA + (size_t)((h) * 128) * lda + ((kt) << 6);  \
    char* _l = (char*)sA + (buf) * 32768 + (h) * 16384 + wave * 1024;         \
    async_copy16(_g, _l);                                                     \
    async_copy16(_g + (size_t)64 * lda, _l + 8192);                           \
  } while (0)
#define STAGE_B(buf, h, kt) do {                                              \
    const __hip_bfloat16* _g = gB + (size_t)((h) * 128) * ldb + ((kt) << 6);  \
    char* _l = (char*)sB + (buf) * 32768 + (h) * 16384 + wave * 1024;         \
    async_copy16(_g, _l);                                                     \
    async_copy16(_g + (size_t)64 * ldb, _l + 8192);                           \
  } while (0)
// B-half for the x128 variant: 64 rows = exactly 512 threads * 16B = 1 copy.
#define STAGE_B1(buf, h, kt) do {                                             \
    const __hip_bfloat16* _g = gB + (size_t)((h) * 64) * ldb + ((kt) << 6);   \
    char* _l = (char*)sB + (buf) * 16384 + (h) * 8192 + wave * 1024;          \
    async_copy16(_g, _l);                                                     \
  } while (0)

#define LOAD_A(aF, lbuf, h) do {                                              \
    const __hip_bfloat16* _b = (lbuf) + (wr * 128 + (h) * 64 + lr) * 64;      \
    _Pragma("unroll")                                                         \
    for (int _i = 0; _i < 4; _i++) {                                          \
      aF[_i][0] = *(const bf16x8*)&_b[_i * 1024 + pc0];                       \
      aF[_i][1] = *(const bf16x8*)&_b[_i * 1024 + pc1];                       \
    }                                                                         \
  } while (0)
#define LOAD_B(bF, lbuf, g) do {                                              \
    const __hip_bfloat16* _b = (lbuf) + (wc * 64 + (g) * 32 + lr) * 64;       \
    _Pragma("unroll")                                                         \
    for (int _j = 0; _j < 2; _j++) {                                          \
      bF[_j][0] = *(const bf16x8*)&_b[_j * 1024 + pc0];                       \
      bF[_j][1] = *(const bf16x8*)&_b[_j * 1024 + pc1];                       \
    }                                                                         \
  } while (0)
#define LOAD_B1(bF, lbuf, g) do {                                             \
    const __hip_bfloat16* _b = (lbuf) + (wc * 32 + (g) * 16 + lr) * 64;       \
    bF[0] = *(const bf16x8*)&_b[pc0];                                         \
    bF[1] = *(const bf16x8*)&_b[pc1];                                         \
  } while (0)

#define MFMA_Q(aF, bF, h, g) do {                                             \
    __builtin_amdgcn_s_setprio(1);                                            \
    _Pragma("unroll")                                                         \
    for (int _i = 0; _i < 4; _i++)                                            \
      _Pragma("unroll")                                                       \
      for (int _j = 0; _j < 2; _j++) {                                        \
        acc[(h) * 4 + _i][(g) * 2 + _j] =                                     \
          __builtin_amdgcn_mfma_f32_16x16x32_bf16(aF[_i][0], bF[_j][0],       \
              acc[(h) * 4 + _i][(g) * 2 + _j], 0, 0, 0);                      \
        acc[(h) * 4 + _i][(g) * 2 + _j] =                                     \
          __builtin_amdgcn_mfma_f32_16x16x32_bf16(aF[_i][1], bF[_j][1],       \
              acc[(h) * 4 + _i][(g) * 2 + _j], 0, 0, 0);                      \
      }                                                                       \
    __builtin_amdgcn_s_setprio(0);                                            \
  } while (0)
#define MFMA_Q1(aF, bF, h, g) do {                                            \
    __builtin_amdgcn_s_setprio(1);                                            \
    _Pragma("unroll")                                                         \
    for (int _i = 0; _i < 4; _i++) {                                          \
      acc[(h) * 4 + _i][(g)] =                                                \
        __builtin_amdgcn_mfma_f32_16x16x32_bf16(aF[_i][0], bF[0],             \
            acc[(h) * 4 + _i][(g)], 0, 0, 0);                                 \
      acc[(h) * 4 + _i][(g)] =                                                \
        __builtin_amdgcn_mfma_f32_16x16x32_bf16(aF[_i][1], bF[1],             \
            acc[(h) * 4 + _i][(g)], 0, 0, 0);                                 \
    }                                                                         \
    __builtin_amdgcn_s_setprio(0);                                            \
  } while (0)

#define ZERO_ACC(acc)                         \
  {                                           \
    f32x4 _z = {0.f, 0.f, 0.f, 0.f};          \
    _Pragma("unroll")                         \
    for (int _i = 0; _i < 8; _i++)            \
      _Pragma("unroll")                       \
      for (int _j = 0; _j < 4; _j++)          \
        acc[_i][_j] = _z;                     \
  }
#define ZERO_ACC2(acc)                        \
  {                                           \
    f32x4 _z = {0.f, 0.f, 0.f, 0.f};          \
    _Pragma("unroll")                         \
    for (int _i = 0; _i < 8; _i++)            \
      _Pragma("unroll")                       \
      for (int _j = 0; _j < 2; _j++)          \
        acc[_i][_j] = _z;                     \
  }

static __device__ __forceinline__ void gemm256(
    const __hip_bfloat16* __restrict__ A, int lda,
    const __hip_bfloat16* __restrict__ Bt, int ldb,
    int K, f32x4 (&acc)[8][4])
{
  __shared__ __hip_bfloat16 sA[2][128 * 64 * 2];   // 64 KiB
  __shared__ __hip_bfloat16 sB[2][128 * 64 * 2];   // 64 KiB

  const int t    = threadIdx.x;   // 0..511
  const int wave = t >> 6;
  const int lane = t & 63;
  const int quad = lane >> 4;
  const int lr   = lane & 15;
  const int wr   = wave >> 2;     // 0..1  (M)
  const int wc   = wave & 3;      // 0..3  (N)

  const int r0 = t >> 3;
  const int cs = (((t & 7) ^ (r0 & 7)) << 3);
  const __hip_bfloat16* gA = A  + (size_t)r0 * lda + cs;
  const __hip_bfloat16* gB = Bt + (size_t)r0 * ldb + cs;

  const int pc0 = ((quad)     ^ (lr & 7)) << 3;
  const int pc1 = ((quad + 4) ^ (lr & 7)) << 3;

  const __hip_bfloat16* const lA0 = sA[0];
  const __hip_bfloat16* const lA1 = sA[1];
  const __hip_bfloat16* const lB0 = sB[0];
  const __hip_bfloat16* const lB1 = sB[1];

  const int nt    = K >> 6;
  const int niter = nt >> 1;

  // prologue: T0 complete (8 copies) + T1 B-lo,B-hi,A-lo (6 in flight).
  STAGE_A(0, 0, 0);
  STAGE_A(0, 1, 0);
  STAGE_B(0, 0, 0);
  STAGE_B(0, 1, 0);
  STAGE_B(1, 0, 1);
  STAGE_B(1, 1, 1);
  STAGE_A(1, 0, 1);
  VMCNT6;
  BAR;

  bf16x8 aF[4][2], bFa[2][2], bFb[2][2];

  for (int j = 0; j < niter - 1; ++j) {
    const int tb = 2 * j + 1, tc = tb + 1, td = tb + 2;

    LOAD_A(aF, lA0, 0); LOAD_B(bFa, lB0, 0);
    STAGE_A(1, 1, tb);
    BAR; MFMA_Q(aF, bFa, 0, 0); BAR;

    LOAD_B(bFb, lB0, 1);
    BAR; MFMA_Q(aF, bFb, 0, 1); BAR;

    LOAD_A(aF, lA0, 1);
    STAGE_B(0, 0, tc);
    BAR; MFMA_Q(aF, bFb, 1, 1); BAR;

    STAGE_B(0, 1, tc);
    STAGE_A(0, 0, tc);
    VMCNT6;
    BAR; MFMA_Q(aF, bFa, 1, 0); BAR;

    LOAD_A(aF, lA1, 0); LOAD_B(bFa, lB1, 0);
    STAGE_A(0, 1, tc);
    BAR; MFMA_Q(aF, bFa, 0, 0); BAR;

    LOAD_B(bFb, lB1, 1);
    BAR; MFMA_Q(aF, bFb, 0, 1); BAR;

    LOAD_A(aF, lA1, 1);
    STAGE_B(1, 0, td);
    BAR; MFMA_Q(aF, bFb, 1, 1); BAR;

    STAGE_B(1, 1, td);
    STAGE_A(1, 0, td);
    VMCNT6;
    BAR; MFMA_Q(aF, bFa, 1, 0); BAR;
  }

  {
    const int tb = nt - 1;
    LOAD_A(aF, lA0, 0); LOAD_B(bFa, lB0, 0);
    STAGE_A(1, 1, tb);
    BAR; MFMA_Q(aF, bFa, 0, 0); BAR;

    LOAD_B(bFb, lB0, 1);
    BAR; MFMA_Q(aF, bFb, 0, 1); BAR;

    LOAD_A(aF, lA0, 1);
    BAR; MFMA_Q(aF, bFb, 1, 1); BAR;

    VMCNT0;
    BAR; MFMA_Q(aF, bFa, 1, 0); BAR;

    LOAD_A(aF, lA1, 0); LOAD_B(bFa, lB1, 0);
    BAR; MFMA_Q(aF, bFa, 0, 0); BAR;

    LOAD_B(bFb, lB1, 1);
    BAR; MFMA_Q(aF, bFb, 0, 1); BAR;

    LOAD_A(aF, lA1, 1);
    BAR; MFMA_Q(aF, bFb, 1, 1); BAR;

    MFMA_Q(aF, bFa, 1, 0);
  }
}

// 256x128 tile, same re-derived ledger; B copies are 1 each -> vmcnt(4).
static __device__ __forceinline__ void gemm256x128(
    const __hip_bfloat16* __restrict__ A, int lda,
    const __hip_bfloat16* __restrict__ Bt, int ldb,
    int K, f32x4 (&acc)[8][2])
{
  __shared__ __hip_bfloat16 sA[2][128 * 64 * 2];   // 64 KiB
  __shared__ __hip_bfloat16 sB[2][64 * 64 * 2];    // 32 KiB

  const int t    = threadIdx.x;
  const int wave = t >> 6;
  const int lane = t & 63;
  const int quad = lane >> 4;
  const int lr   = lane & 15;
  const int wr   = wave >> 2;     // 0..1  (M)
  const int wc   = wave & 3;      // 0..3  (N, 32 cols each)

  const int r0 = t >> 3;
  const int cs = (((t & 7) ^ (r0 & 7)) << 3);
  const __hip_bfloat16* gA = A  + (size_t)r0 * lda + cs;
  const __hip_bfloat16* gB = Bt + (size_t)r0 * ldb + cs;

  const int pc0 = ((quad)     ^ (lr & 7)) << 3;
  const int pc1 = ((quad + 4) ^ (lr & 7)) << 3;

  const __hip_bfloat16* const lA0 = sA[0];
  const __hip_bfloat16* const lA1 = sA[1];
  const __hip_bfloat16* const lB0 = sB[0];
  const __hip_bfloat16* const lB1 = sB[1];

  const int nt    = K >> 6;
  const int niter = nt >> 1;

  // prologue: T0 complete (6 copies) + T1 B-lo,B-hi,A-lo (4 in flight).
  STAGE_A(0, 0, 0);
  STAGE_A(0, 1, 0);
  STAGE_B1(0, 0, 0);
  STAGE_B1(0, 1, 0);
  STAGE_B1(1, 0, 1);
  STAGE_B1(1, 1, 1);
  STAGE_A(1, 0, 1);
  VMCNT4;                 // drains T0's 6; T1's 4 stay in flight
  BAR;

  bf16x8 aF[4][2], bFa[2], bFb[2];

  for (int j = 0; j < niter - 1; ++j) {
    const int tb = 2 * j + 1, tc = tb + 1, td = tb + 2;

    LOAD_A(aF, lA0, 0); LOAD_B1(bFa, lB0, 0);
    STAGE_A(1, 1, tb);
    BAR; MFMA_Q1(aF, bFa, 0, 0); BAR;

    LOAD_B1(bFb, lB0, 1);
    BAR; MFMA_Q1(aF, bFb, 0, 1); BAR;

    LOAD_A(aF, lA0, 1);
    STAGE_B1(0, 0, tc);
    BAR; MFMA_Q1(aF, bFb, 1, 1); BAR;

    STAGE_B1(0, 1, tc);
    STAGE_A(0, 0, tc);
    VMCNT4;               // drain buf1's 6 (of 10)
    BAR; MFMA_Q1(aF, bFa, 1, 0); BAR;

    LOAD_A(aF, lA1, 0); LOAD_B1(bFa, lB1, 0);
    STAGE_A(0, 1, tc);
    BAR; MFMA_Q1(aF, bFa, 0, 0); BAR;

    LOAD_B1(bFb, lB1, 1);
    BAR; MFMA_Q1(aF, bFb, 0, 1); BAR;

    LOAD_A(aF, lA1, 1);
    STAGE_B1(1, 0, td);
    BAR; MFMA_Q1(aF, bFb, 1, 1); BAR;

    STAGE_B1(1, 1, td);
    STAGE_A(1, 0, td);
    VMCNT4;               // drain buf0's 6 (of 10)
    BAR; MFMA_Q1(aF, bFa, 1, 0); BAR;
  }

  { // final pair
    const int tb = nt - 1;
    LOAD_A(aF, lA0, 0); LOAD_B1(bFa, lB0, 0);
    STAGE_A(1, 1, tb);
    BAR; MFMA_Q1(aF, bFa, 0, 0); BAR;

    LOAD_B1(bFb, lB0, 1);
    BAR; MFMA_Q1(aF, bFb, 0, 1); BAR;

    LOAD_A(aF, lA0, 1);
    BAR; MFMA_Q1(aF, bFb, 1, 1); BAR;

    VMCNT0;
    BAR; MFMA_Q1(aF, bFa, 1, 0); BAR;

    LOAD_A(aF, lA1, 0); LOAD_B1(bFa, lB1, 0);
    BAR; MFMA_Q1(aF, bFa, 0, 0); BAR;

    LOAD_B1(bFb, lB1, 1);
    BAR; MFMA_Q1(aF, bFb, 0, 1); BAR;

    LOAD_A(aF, lA1, 1);
    BAR; MFMA_Q1(aF, bFb, 1, 1); BAR;

    MFMA_Q1(aF, bFa, 1, 0);
  }
}

// ---------------- fused prep: z<3 -> transpose+cast W; z==3 -> cast x ----------------
__global__ __launch_bounds__(256) void prep_kernel(
    const float* __restrict__ x,
    const float* __restrict__ Wq,
    const float* __restrict__ Wk,
    const float* __restrict__ Wv,
    __hip_bfloat16* __restrict__ xb,
    __hip_bfloat16* __restrict__ Wt3)
{
  const int tx = threadIdx.x, ty = threadIdx.y;  // (32,8)
  if (blockIdx.z == 3) {
    const int tid = ty * 32 + tx;
    const size_t base = ((size_t)blockIdx.y * 32 + blockIdx.x) * 8192;
#pragma unroll
    for (int p = 0; p < 8; p++) {
      const size_t i = base + p * 1024 + tid * 4;
      const float4 v = *(const float4*)(x + i);
      __hip_bfloat16 o[4] = {__float2bfloat16(v.x), __float2bfloat16(v.y),
                             __float2bfloat16(v.z), __float2bfloat16(v.w)};
      *(uint64_t*)(xb + i) = *(uint64_t*)o;
    }
    return;
  }
  const float* src = (blockIdx.z == 0) ? Wq : (blockIdx.z == 1) ? Wk : Wv;
  __hip_bfloat16* dst = Wt3 + (size_t)blockIdx.z * D_EMB * D_EMB;
  __shared__ __hip_bfloat16 tile[32][33];
  const int x0 = blockIdx.x * 32;  // e
  const int y0 = blockIdx.y * 32;  // d
#pragma unroll
  for (int i = 0; i < 32; i += 8)
    tile[ty + i][tx] = __float2bfloat16(src[(size_t)(y0 + ty + i) * D_EMB + (x0 + tx)]);
  __syncthreads();
#pragma unroll
  for (int i = 0; i < 32; i += 8)
    dst[(size_t)(x0 + ty + i) * D_EMB + (y0 + tx)] = tile[tx][ty + i];
}

// ---------------- QKV projections (per-tile 256^2, 8-phase) ----------------
// grid (32 m-tiles, 4 n-tiles, 3 mats), m fastest.
// z=0: Q[b][s][e], z=1: K[b][s][e], z=2: V transposed -> Vt[b][e][s]
__global__ __launch_bounds__(512, 2) void qkv_kernel(
    const __hip_bfloat16* __restrict__ xb,
    const __hip_bfloat16* __restrict__ Wt3,
    const float* __restrict__ bq,
    const float* __restrict__ bk,
    const float* __restrict__ bv,
    __hip_bfloat16* __restrict__ Q,
    __hip_bfloat16* __restrict__ Kb,
    __hip_bfloat16* __restrict__ Vt)
{
  const int mat = blockIdx.z;
  const int m0  = blockIdx.x * 256;
  const int n0  = blockIdx.y * 256;

  f32x4 acc[8][4];
  ZERO_ACC(acc);

  gemm256(xb + (size_t)m0 * D_EMB, D_EMB,
          Wt3 + (size_t)mat * D_EMB * D_EMB + (size_t)n0 * D_EMB, D_EMB,
          D_EMB, acc);

  const float* bias = (mat == 0) ? bq : (mat == 1) ? bk : bv;

  const int t = threadIdx.x;
  const int wave = t >> 6, lane = t & 63;
  const int quad = lane >> 4, lr = lane & 15;
  const int wr = wave >> 2, wc = wave & 3;

#pragma unroll
  for (int i = 0; i < 8; i++) {
#pragma unroll
    for (int j = 0; j < 4; j++) {
      const int n = n0 + wc * 64 + j * 16 + lr;
      const float bb = bias[n];
      const int mbase = m0 + wr * 128 + i * 16 + quad * 4;
      if (mat == 2) {
        const int b = mbase >> 11, s = mbase & 2047;
        __hip_bfloat16 pk[4];
#pragma unroll
        for (int r = 0; r < 4; r++) pk[r] = __float2bfloat16(acc[i][j][r] + bb);
        *(uint64_t*)&Vt[(size_t)b * D_EMB * SEQ + (size_t)n * SEQ + s] = *(uint64_t*)pk;
      } else {
        __hip_bfloat16* dst = (mat == 0) ? Q : Kb;
#pragma unroll
        for (int r = 0; r < 4; r++)
          dst[(size_t)(mbase + r) * D_EMB + n] = __float2bfloat16(acc[i][j][r] + bb);
      }
    }
  }
}

// ---------------- scores = Q @ K^T * scale (fp16 out) ----------------
__global__ __launch_bounds__(512, 2) void scores_kernel(
    const __hip_bfloat16* __restrict__ Q,
    const __hip_bfloat16* __restrict__ Kb,
    __half* __restrict__ Sc)
{
  const int b  = blockIdx.z;
  const int m0 = blockIdx.y * 256;  // s_q
  const int n0 = blockIdx.x * 256;  // s_k

  f32x4 acc[8][4];
  ZERO_ACC(acc);

  gemm256(Q  + (size_t)b * SEQ * D_EMB + (size_t)m0 * D_EMB, D_EMB,
          Kb + (size_t)b * SEQ * D_EMB + (size_t)n0 * D_EMB, D_EMB,
          D_EMB, acc);

  __half* out = Sc + (size_t)b * SEQ * SEQ;
  const float scale = 0.03125f;  // 1/sqrt(1024)

  const int t = threadIdx.x;
  const int wave = t >> 6, lane = t & 63;
  const int quad = lane >> 4, lr = lane & 15;
  const int wr = wave >> 2, wc = wave & 3;

#pragma unroll
  for (int i = 0; i < 8; i++)
#pragma unroll
    for (int j = 0; j < 4; j++) {
      const int n = n0 + wc * 64 + j * 16 + lr;
#pragma unroll
      for (int r = 0; r < 4; r++) {
        const int m = m0 + wr * 128 + i * 16 + quad * 4 + r;
        out[(size_t)m * SEQ + n] = __float2half(acc[i][j][r] * scale);
      }
    }
}

// ---------------- row softmax: fp16 scores -> bf16 probs (16B vectorized) ----------------
__global__ __launch_bounds__(256) void softmax_kernel(
    const __half* __restrict__ Sc, __hip_bfloat16* __restrict__ P)
{
  const int row = blockIdx.x;  // 0..8191
  const __half* src = Sc + (size_t)row * SEQ;
  const int t = threadIdx.x;
  const int wave = t >> 6, lane = t & 63;

  const short8 raw = *(const short8*)(src + t * 8);
  float v[8];
#pragma unroll
  for (int i = 0; i < 8; i++) {
    const short si = raw[i];
    __half h;
    memcpy(&h, &si, sizeof(h));
    v[i] = __half2float(h);
  }

  float m = v[0];
#pragma unroll
  for (int i = 1; i < 8; i++) m = fmaxf(m, v[i]);
#pragma unroll
  for (int o = 32; o > 0; o >>= 1) m = fmaxf(m, __shfl_xor(m, o));

  __shared__ float redm[4];
  __shared__ float reds[4];
  if (lane == 0) redm[wave] = m;
  __syncthreads();
  m = fmaxf(fmaxf(redm[0], redm[1]), fmaxf(redm[2], redm[3]));

  float e[8], s = 0.f;
#pragma unroll
  for (int i = 0; i < 8; i++) { e[i] = __expf(v[i] - m); s += e[i]; }
#pragma unroll
  for (int o = 32; o > 0; o >>= 1) s += __shfl_xor(s, o);
  if (lane == 0) reds[wave] = s;
  __syncthreads();
  s = reds[0] + reds[1] + reds[2] + reds[3];

  const float inv = 1.f / s;
  short8 outp;
#pragma unroll
  for (int i = 0; i < 8; i++) {
    const __hip_bfloat16 b = __float2bfloat16(e[i] * inv);
    short sb;
    memcpy(&sb, &b, sizeof(sb));
    outp[i] = sb;
  }
  *(short8*)(P + (size_t)row * SEQ + t * 8) = outp;
}

// ---------------- out(fp32) = P @ V  (256x128 tiles -> 256 blocks, 1 round) ----------------
__global__ __launch_bounds__(512, 2) void pv_kernel(
    const __hip_bfloat16* __restrict__ P,
    const __hip_bfloat16* __restrict__ Vt,
    float* __restrict__ out)
{
  const int b  = blockIdx.z;
  const int m0 = blockIdx.y * 256;  // s_q
  const int n0 = blockIdx.x * 128;  // e

  f32x4 acc[8][2];
  ZERO_ACC2(acc);

  gemm256x128(P  + (size_t)b * SEQ * SEQ   + (size_t)m0 * SEQ, SEQ,
              Vt + (size_t)b * D_EMB * SEQ + (size_t)n0 * SEQ, SEQ,
              SEQ, acc);

  float* o = out + (size_t)b * SEQ * D_EMB;

  const int t = threadIdx.x;
  const int wave = t >> 6, lane = t & 63;
  const int quad = lane >> 4, lr = lane & 15;
  const int wr = wave >> 2, wc = wave & 3;

#pragma unroll
  for (int i = 0; i < 8; i++)
#pragma unroll
    for (int j = 0; j < 2; j++) {
      const int n = n0 + wc * 32 + j * 16 + lr;
#pragma unroll
      for (int r = 0; r < 4; r++) {
        const int m = m0 + wr * 128 + i * 16 + quad * 4 + r;
        o[(size_t)m * D_EMB + n] = acc[i][j][r];
      }
    }
}

extern "C" void kernel_launch(void* const* d_in, const int* in_sizes, int n_in,
                              void* d_out, int out_size, void* d_ws, size_t ws_size,
                              hipStream_t stream) {
  const float* x  = (const float*)d_in[0];
  const float* Wq = (const float*)d_in[1];
  const float* bq = (const float*)d_in[2];
  const float* Wk = (const float*)d_in[3];
  const float* bk = (const float*)d_in[4];
  const float* Wv = (const float*)d_in[5];
  const float* bv = (const float*)d_in[6];
  float* out = (float*)d_out;

  char* ws = (char*)d_ws;
  __hip_bfloat16* xb  = (__hip_bfloat16*)(ws);
  __hip_bfloat16* Wt3 = (__hip_bfloat16*)(ws + 16777216);
  __hip_bfloat16* Q   = (__hip_bfloat16*)(ws + 23068672);
  __hip_bfloat16* Kb  = (__hip_bfloat16*)(ws + 39845888);
  __hip_bfloat16* Vt  = (__hip_bfloat16*)(ws + 56623104);
  __half*         Sc  = (__half*)        (ws + 73400320);   // 32 MB fp16
  __hip_bfloat16* P   = (__hip_bfloat16*)(ws + 140509184);
  // total = 140509184 + 33554432 = 174,063,616 bytes (~166 MB)

  prep_kernel  <<<dim3(32, 32, 4), dim3(32, 8), 0, stream>>>(x, Wq, Wk, Wv, xb, Wt3);
  qkv_kernel   <<<dim3(32, 4, 3),  512,        0, stream>>>(xb, Wt3, bq, bk, bv, Q, Kb, Vt);
  scores_kernel<<<dim3(8, 8, 4),   512,        0, stream>>>(Q, Kb, Sc);
  softmax_kernel<<<dim3(8192),     256,        0, stream>>>(Sc, P);
  pv_kernel    <<<dim3(8, 8, 4),   512,        0, stream>>>(P, Vt, out);
}